// Round 8
// baseline (526.876 us; speedup 1.0000x reference)
//
#include <hip/hip_runtime.h>
#include <hip/hip_bf16.h>

typedef unsigned short u16;
typedef __bf16 bf16x8 __attribute__((ext_vector_type(8)));
typedef float floatx4 __attribute__((ext_vector_type(4)));
typedef float floatx2 __attribute__((ext_vector_type(2)));
typedef unsigned uintx4 __attribute__((ext_vector_type(4)));
typedef unsigned short ushortx4 __attribute__((ext_vector_type(4)));

static constexpr int D = 128;

__device__ inline float bflo(unsigned u) { return __uint_as_float(u << 16); }
__device__ inline float bfhi(unsigned u) { return __uint_as_float(u & 0xffff0000u); }
__device__ inline unsigned packbf(float a, float b) {
    unsigned lo = __hip_bfloat16_raw(__float2bfloat16(a)).x;
    unsigned hi = __hip_bfloat16_raw(__float2bfloat16(b)).x;
    return lo | (hi << 16);
}

// ---------------- zero ints ----------------
__global__ void zero_int_kernel(int* __restrict__ p, int n) {
    int i = blockIdx.x * blockDim.x + threadIdx.x;
    int stride = gridDim.x * blockDim.x;
    for (; i < n; i += stride) p[i] = 0;
}

// ---------------- merged prep: convert x | count3 | pack weights ----------------
static constexpr int CVB = 1024;  // convert blocks

__global__ void prep_kernel(const float* __restrict__ x, u16* __restrict__ xb, int n4,
                            const int* __restrict__ dst0, const int* __restrict__ dst1,
                            const int* __restrict__ dst2, int* __restrict__ counts,
                            int E, int N, int cb3,
                            const float* __restrict__ WC, const float* __restrict__ WA0,
                            const float* __restrict__ WA1, const float* __restrict__ WA2,
                            u16* __restrict__ Wp) {
    int b = blockIdx.x;
    if (b < CVB) {
        int i = b * blockDim.x + threadIdx.x;
        int stride = CVB * blockDim.x;
        for (; i < n4; i += stride) {
            floatx4 v = __builtin_nontemporal_load((const floatx4*)x + i);
            ushortx4 o;
            o.x = __hip_bfloat16_raw(__float2bfloat16(v.x)).x;
            o.y = __hip_bfloat16_raw(__float2bfloat16(v.y)).x;
            o.z = __hip_bfloat16_raw(__float2bfloat16(v.z)).x;
            o.w = __hip_bfloat16_raw(__float2bfloat16(v.w)).x;
            *((ushortx4*)xb + i) = o;
        }
    } else if (b < CVB + cb3) {
        int i = (b - CVB) * blockDim.x + threadIdx.x;
        if (i < E) {
            atomicAdd(&counts[dst0[i]], 1);
        } else if (i < 2 * E) {
            atomicAdd(&counts[N + dst1[i - E]], 1);
        } else if (i < 3 * E) {
            atomicAdd(&counts[2 * N + dst2[i - 2 * E]], 1);
        }
    } else {
        // Wp (u16): [0,16384)=WC^T, [16384,32768)=WA0, [32768,65536)=WA1, [65536,114688)=WA2
        int c = (b - CVB - cb3) * blockDim.x + threadIdx.x;
        if (c >= 14336) return;
        const float* W;
        int K, transposed, cl;
        u16* out;
        if (c < 2048) {
            W = WC; K = 128; transposed = 1; cl = c; out = Wp;
        } else if (c < 4096) {
            W = WA0; K = 128; transposed = 0; cl = c - 2048; out = Wp + 16384;
        } else if (c < 8192) {
            W = WA1; K = 256; transposed = 0; cl = c - 4096; out = Wp + 32768;
        } else {
            W = WA2; K = 384; transposed = 0; cl = c - 8192; out = Wp + 65536;
        }
        int s = cl >> 9, rem = cl & 511, t = rem >> 6, l = rem & 63;
        int kbase = 32 * s + ((l >> 4) * 8);
        int n = 16 * t + (l & 15);
#pragma unroll
        for (int j = 0; j < 8; ++j) {
            int k = kbase + j;
            float w = transposed ? W[n * K + k] : W[k * D + n];
            out[(size_t)cl * 8 + j] = __hip_bfloat16_raw(__float2bfloat16(w)).x;
        }
    }
}

// ---------------- offsets: wave scan + one atomic per wave ----------------
__global__ __launch_bounds__(256) void offs_kernel(const int* __restrict__ counts,
                                                   int* __restrict__ offs,
                                                   int* __restrict__ cursor,
                                                   int* __restrict__ counters,
                                                   int N, int bpt) {
    int type = blockIdx.x / bpt;
    int n = (blockIdx.x - type * bpt) * 256 + threadIdx.x;
    int lane = threadIdx.x & 63;
    int i = type * N + n;
    int v = (n < N) ? counts[i] : 0;
    int incl = v;
#pragma unroll
    for (int d = 1; d < 64; d <<= 1) {
        int t = __shfl_up(incl, d, 64);
        if (lane >= d) incl += t;
    }
    int total = __shfl(incl, 63, 64);
    int base = 0;
    if (lane == 63) base = atomicAdd(&counters[type], total);
    base = __shfl(base, 63, 64);
    int off = base + incl - v;
    if (n < N) {
        offs[i] = off;
        cursor[i] = off;
    }
}

// ---------------- CSR scatter (all three edge types, one launch) ----------------
// csr2 PADDED to stride 4: one aligned 16B store; pad slot = 0 (valid row id,
// value discarded by aggregate's tail predication).
__global__ void scatter3_kernel(const int* __restrict__ dst0, const int* __restrict__ src0,
                                const int* __restrict__ dst1, const int* __restrict__ src1,
                                const int* __restrict__ dst2, const int* __restrict__ src2,
                                int* __restrict__ cursor,
                                int* __restrict__ csr0, int* __restrict__ csr1,
                                int* __restrict__ csr2, int E, int N) {
    int i = blockIdx.x * blockDim.x + threadIdx.x;
    if (i < E) {
        int d = __builtin_nontemporal_load(dst0 + i);
        int pos = atomicAdd(&cursor[d], 1);
        csr0[pos] = __builtin_nontemporal_load(src0 + i);
    } else if (i < 2 * E) {
        int e = i - E;
        int d = __builtin_nontemporal_load(dst1 + e);
        int pos = atomicAdd(&cursor[N + d], 1);
        csr1[pos * 2] = __builtin_nontemporal_load(src1 + e * 2);
        csr1[pos * 2 + 1] = __builtin_nontemporal_load(src1 + e * 2 + 1);
    } else if (i < 3 * E) {
        int e = i - 2 * E;
        int d = __builtin_nontemporal_load(dst2 + e);
        int pos = atomicAdd(&cursor[2 * N + d], 1);
        int a = __builtin_nontemporal_load(src2 + e * 3);
        int b = __builtin_nontemporal_load(src2 + e * 3 + 1);
        int c = __builtin_nontemporal_load(src2 + e * 3 + 2);
        int4 o; o.x = a; o.y = b; o.z = c; o.w = 0;
        *(int4*)(csr2 + (size_t)pos * 4) = o;
    }
}

// ---------------- per-node aggregation: one row per wave, lane owns 2 columns ----------------
// R7 structure kept verbatim (probe-confirmed at the ~4.2 TB/s fabric roofline).
template <int A>
__device__ inline void agg_wave(const u16* __restrict__ xb, const int* __restrict__ csr,
                                int o0, int deg, int lane, u16* __restrict__ outp) {
    constexpr int ST = (A == 3) ? 4 : A;  // csr stride per edge (csr2 padded)
    constexpr int CH_E = (A == 1) ? 12 : (A == 2) ? 10 : 8;  // edges per chunk
    constexpr int CH = CH_E * ST;         // csr items per chunk (12/20/32)
    floatx2 acc[A];
#pragma unroll
    for (int s = 0; s < A; ++s) acc[s] = floatx2{0.f, 0.f};
    const int base = o0 * ST;
    const int last = base + deg * ST - 1;
    const unsigned* __restrict__ xw = (const unsigned*)xb;

    for (int e0 = 0; e0 < deg; e0 += CH_E) {
        int rv = 0;
        if (lane < CH) {
            int idx = base + e0 * ST + lane;
            if (idx > last) idx = last;  // clamp, never guard
            rv = csr[idx];
        }
        int erem = deg - e0;  // wave-uniform
        unsigned u[CH_E][A];
        // ---- issue ALL gathers for this chunk, unconditionally ----
#pragma unroll
        for (int ke = 0; ke < CH_E; ++ke)
#pragma unroll
            for (int s = 0; s < A; ++s) {
                int r = __builtin_amdgcn_readlane(rv, ke * ST + s);  // SGPR row id
                u[ke][s] = xw[((size_t)(unsigned)r << 6) + lane];
            }
        if (erem >= CH_E) {
#pragma unroll
            for (int ke = 0; ke < CH_E; ++ke)
#pragma unroll
                for (int s = 0; s < A; ++s) {
                    floatx2 f = {bflo(u[ke][s]), bfhi(u[ke][s])};
                    acc[s] += f;
                }
        } else {
#pragma unroll
            for (int ke = 0; ke < CH_E; ++ke) {
                bool ok = ke < erem;
#pragma unroll
                for (int s = 0; s < A; ++s) {
                    unsigned uz = ok ? u[ke][s] : 0u;
                    floatx2 f = {bflo(uz), bfhi(uz)};
                    acc[s] += f;
                }
            }
        }
    }

    float norm = (deg > 0) ? 1.0f / (float)deg : 0.0f;
#pragma unroll
    for (int s = 0; s < A; ++s) {
        unsigned o = packbf(acc[s].x * norm, acc[s].y * norm);
        ((unsigned*)(outp + s * D))[lane] = o;  // normal store: gemm re-reads AG
    }
}

// Round-8: one kernel PER TYPE (diagnostic split — drops each dispatch below
// the remainder kernels so top-5 finally reveals the real #2/#3 consumers;
// also removes the type branch). cnt/off passed pre-offset by type*N.
template <int A>
__global__ __launch_bounds__(256) void agg_kernel(
    const u16* __restrict__ xb, const int* __restrict__ cnt, const int* __restrict__ off,
    const int* __restrict__ csr, u16* __restrict__ AG, int outOff, int n0, int M) {
    int w = __builtin_amdgcn_readfirstlane(threadIdx.x >> 6);
    int l = blockIdx.x * 4 + w;
    if (l >= M) return;
    int lane = threadIdx.x & 63;
    int n = n0 + l;
    int o0 = __builtin_amdgcn_readfirstlane(off[n]);
    int dg = __builtin_amdgcn_readfirstlane(cnt[n]);
    agg_wave<A>(xb, csr, o0, dg, lane, AG + (size_t)l * 768 + outOff);
}

// ---------------- fused final GEMM: out = [x | AG] @ [WC^T; WA*] + bC ----------------
// Round-8: BARRIER-FREE. A-fragments are wave-private (each wave owns its 32
// rows), so LDS staging gave no sharing — only coalescing. Each lane now loads
// its 16B A-fragment directly from xb/AG (16B-aligned), B-fragments directly
// from L2-hot Wp. Zero __syncthreads in the K-loop -> no vmcnt(0) drains; the
// compiler pipelines loads across ksteps. Two independent MFMA chains (strips)
// interleaved for ILP.
__global__ __launch_bounds__(256) void final_gemm_kernel(
    const u16* __restrict__ xb, const u16* __restrict__ AG, const u16* __restrict__ Wp,
    const float* __restrict__ bC, float* __restrict__ out, int n0, int M) {
    constexpr int KSTEPS = 14;  // 896 / 64
    const int tid = threadIdx.x;
    const int wave = tid >> 6;
    const int lane = tid & 63;
    const int m0 = blockIdx.x * 128;

    // per-strip rows (strip0 = wave*32 + (lane&15), strip1 = +16), clamped
    int r0 = wave * 32 + (lane & 15);
    int e0 = m0 + r0, e1 = e0 + 16;
    int l0 = (e0 < M) ? e0 : 0;
    int l1 = (e1 < M) ? e1 : 0;
    int g0 = (e0 < M) ? (n0 + e0) : n0;
    int g1 = (e1 < M) ? (n0 + e1) : n0;
    const int co = (lane >> 4) * 8;  // u16 col offset within the 64-col kstep

    const u16* xp0 = xb + (size_t)g0 * D + co;
    const u16* xp1 = xb + (size_t)g1 * D + co;
    const u16* ap0 = AG + (size_t)l0 * 768 + co;
    const u16* ap1 = AG + (size_t)l1 * 768 + co;
    const u16* wp = Wp + (size_t)lane * 8;

    floatx4 acc[2][8];
#pragma unroll
    for (int s = 0; s < 2; ++s)
#pragma unroll
        for (int t = 0; t < 8; ++t) acc[s][t] = floatx4{0.f, 0.f, 0.f, 0.f};

    for (int ks = 0; ks < KSTEPS; ++ks) {
        const u16* a0;
        const u16* a1;
        if (ks < 2) {
            a0 = xp0 + ks * 64;
            a1 = xp1 + ks * 64;
        } else {
            a0 = ap0 + (ks - 2) * 64;
            a1 = ap1 + (ks - 2) * 64;
        }
        bf16x8 af0[2], af1[2];
        af0[0] = *(const bf16x8*)(a0);
        af0[1] = *(const bf16x8*)(a0 + 32);
        af1[0] = *(const bf16x8*)(a1);
        af1[1] = *(const bf16x8*)(a1 + 32);
        const u16* wks = wp + (size_t)ks * 8192;
#pragma unroll
        for (int sub = 0; sub < 2; ++sub) {
#pragma unroll
            for (int t = 0; t < 8; ++t) {
                bf16x8 bfrag = *(const bf16x8*)(wks + (size_t)((sub * 8 + t) * 64) * 8);
                acc[0][t] = __builtin_amdgcn_mfma_f32_16x16x32_bf16(af0[sub], bfrag,
                                                                    acc[0][t], 0, 0, 0);
                acc[1][t] = __builtin_amdgcn_mfma_f32_16x16x32_bf16(af1[sub], bfrag,
                                                                    acc[1][t], 0, 0, 0);
            }
        }
    }

#pragma unroll
    for (int strip = 0; strip < 2; ++strip) {
#pragma unroll
        for (int r = 0; r < 4; ++r) {
            int row = wave * 32 + strip * 16 + (lane >> 4) * 4 + r;
            int e = m0 + row;
            if (e >= M) continue;
            size_t base = (size_t)(n0 + e) * D;
#pragma unroll
            for (int t = 0; t < 8; ++t) {
                int col = 16 * t + (lane & 15);
                out[base + col] = acc[strip][t][r] + bC[col];
            }
        }
    }
}

extern "C" void kernel_launch(void* const* d_in, const int* in_sizes, int n_in,
                              void* d_out, int out_size, void* d_ws, size_t ws_size,
                              hipStream_t stream) {
    const float* x = (const float*)d_in[0];
    const int* src0 = (const int*)d_in[1];
    const int* dst0 = (const int*)d_in[2];
    const int* src1 = (const int*)d_in[3];
    const int* dst1 = (const int*)d_in[4];
    const int* src2 = (const int*)d_in[5];
    const int* dst2 = (const int*)d_in[6];
    const float* WA0 = (const float*)d_in[7];
    const float* WA1 = (const float*)d_in[8];
    const float* WA2 = (const float*)d_in[9];
    const float* WC = (const float*)d_in[10];
    const float* bC = (const float*)d_in[11];

    const int N = in_sizes[0] / D;  // 100000
    const int E = in_sizes[2];      // 500000

    auto align256 = [](size_t v) { return (v + 255) & ~(size_t)255; };
    char* ws = (char*)d_ws;
    size_t ofs = 0;
    u16* xb = (u16*)(ws + ofs);      ofs = align256(ofs + (size_t)N * D * sizeof(u16));
    int* counts = (int*)(ws + ofs);  ofs = align256(ofs + ((size_t)3 * N + 4) * sizeof(int));
    int* counters = counts + 3 * N;  // 3 ints, zeroed with counts
    int* offs = (int*)(ws + ofs);    ofs = align256(ofs + (size_t)3 * N * sizeof(int));
    int* cursor = (int*)(ws + ofs);  ofs = align256(ofs + (size_t)3 * N * sizeof(int));
    int* csr0 = (int*)(ws + ofs);    // E ints
    int* csr1 = csr0 + E;            // 2E ints
    int* csr2 = csr1 + 2 * E;        // 4E ints (stride-4 padded)
    ofs = align256(ofs + (size_t)7 * E * sizeof(int));
    u16* Wp = (u16*)(ws + ofs);      ofs = align256(ofs + (size_t)896 * D * sizeof(u16));
    u16* AG = (u16*)(ws + ofs);

    size_t avail = (ws_size > ofs) ? (ws_size - ofs) : 0;
    long long ncMax = (long long)(avail / (768 * sizeof(u16)));
    int Nc = (int)((ncMax / 128) * 128);
    if (Nc > N) Nc = ((N + 127) / 128) * 128;
    if (Nc < 128) Nc = 128;

    // prep
    zero_int_kernel<<<512, 256, 0, stream>>>(counts, 3 * N + 4);

    int cb3 = (3 * E + 255) / 256;
    int packb = (14336 + 255) / 256;  // 56
    prep_kernel<<<CVB + cb3 + packb, 256, 0, stream>>>(x, xb, N * D / 4,
                                                       dst0, dst1, dst2, counts, E, N, cb3,
                                                       WC, WA0, WA1, WA2, Wp);

    int bpt = (N + 255) / 256;
    offs_kernel<<<3 * bpt, 256, 0, stream>>>(counts, offs, cursor, counters, N, bpt);

    scatter3_kernel<<<cb3, 256, 0, stream>>>(dst0, src0, dst1, src1, dst2, src2,
                                             cursor, csr0, csr1, csr2, E, N);

    for (int n0 = 0; n0 < N; n0 += Nc) {
        int M = (N - n0 < Nc) ? (N - n0) : Nc;
        int ab = (M + 3) / 4;
        agg_kernel<1><<<ab, 256, 0, stream>>>(xb, counts, offs, csr0, AG, 0, n0, M);
        agg_kernel<2><<<ab, 256, 0, stream>>>(xb, counts + N, offs + N, csr1, AG, 128, n0, M);
        agg_kernel<3><<<ab, 256, 0, stream>>>(xb, counts + 2 * N, offs + 2 * N, csr2, AG, 384, n0, M);
        final_gemm_kernel<<<(M + 127) / 128, 256, 0, stream>>>(xb, AG, Wp, bC,
                                                               (float*)d_out, n0, M);
    }
}

// Round 10
// 387.868 us; speedup vs baseline: 1.3584x; 1.3584x over previous
//
#include <hip/hip_runtime.h>
#include <hip/hip_bf16.h>

typedef unsigned short u16;
typedef unsigned long long u64;
typedef __bf16 bf16x8 __attribute__((ext_vector_type(8)));
typedef float floatx4 __attribute__((ext_vector_type(4)));
typedef float floatx2 __attribute__((ext_vector_type(2)));
typedef unsigned uintx4 __attribute__((ext_vector_type(4)));
typedef unsigned short ushortx4 __attribute__((ext_vector_type(4)));

static constexpr int D = 128;
static constexpr int BSH = 10;      // 1024 nodes per bucket
static constexpr int MAXNB = 128;   // max buckets (N <= 131072)

__device__ inline float bflo(unsigned u) { return __uint_as_float(u << 16); }
__device__ inline float bfhi(unsigned u) { return __uint_as_float(u & 0xffff0000u); }
__device__ inline unsigned packbf(float a, float b) {
    unsigned lo = __hip_bfloat16_raw(__float2bfloat16(a)).x;
    unsigned hi = __hip_bfloat16_raw(__float2bfloat16(b)).x;
    return lo | (hi << 16);
}

// ---------------- zero ints ----------------
__global__ void zero_int_kernel(int* __restrict__ p, int n) {
    int i = blockIdx.x * blockDim.x + threadIdx.x;
    int stride = gridDim.x * blockDim.x;
    for (; i < n; i += stride) p[i] = 0;
}

// ---------------- merged prep: convert x | count3 | pack weights ----------------
static constexpr int CVB = 1024;  // convert blocks

__global__ void prep_kernel(const float* __restrict__ x, u16* __restrict__ xb, int n4,
                            const int* __restrict__ dst0, const int* __restrict__ dst1,
                            const int* __restrict__ dst2, int* __restrict__ counts,
                            int E, int N, int cb3,
                            const float* __restrict__ WC, const float* __restrict__ WA0,
                            const float* __restrict__ WA1, const float* __restrict__ WA2,
                            u16* __restrict__ Wp) {
    int b = blockIdx.x;
    if (b < CVB) {
        int i = b * blockDim.x + threadIdx.x;
        int stride = CVB * blockDim.x;
        for (; i < n4; i += stride) {
            floatx4 v = __builtin_nontemporal_load((const floatx4*)x + i);
            ushortx4 o;
            o.x = __hip_bfloat16_raw(__float2bfloat16(v.x)).x;
            o.y = __hip_bfloat16_raw(__float2bfloat16(v.y)).x;
            o.z = __hip_bfloat16_raw(__float2bfloat16(v.z)).x;
            o.w = __hip_bfloat16_raw(__float2bfloat16(v.w)).x;
            *((ushortx4*)xb + i) = o;
        }
    } else if (b < CVB + cb3) {
        int i = (b - CVB) * blockDim.x + threadIdx.x;
        if (i < E) {
            atomicAdd(&counts[dst0[i]], 1);
        } else if (i < 2 * E) {
            atomicAdd(&counts[N + dst1[i - E]], 1);
        } else if (i < 3 * E) {
            atomicAdd(&counts[2 * N + dst2[i - 2 * E]], 1);
        }
    } else {
        // Wp (u16): [0,16384)=WC^T, [16384,32768)=WA0, [32768,65536)=WA1, [65536,114688)=WA2
        int c = (b - CVB - cb3) * blockDim.x + threadIdx.x;
        if (c >= 14336) return;
        const float* W;
        int K, transposed, cl;
        u16* out;
        if (c < 2048) {
            W = WC; K = 128; transposed = 1; cl = c; out = Wp;
        } else if (c < 4096) {
            W = WA0; K = 128; transposed = 0; cl = c - 2048; out = Wp + 16384;
        } else if (c < 8192) {
            W = WA1; K = 256; transposed = 0; cl = c - 4096; out = Wp + 32768;
        } else {
            W = WA2; K = 384; transposed = 0; cl = c - 8192; out = Wp + 65536;
        }
        int s = cl >> 9, rem = cl & 511, t = rem >> 6, l = rem & 63;
        int kbase = 32 * s + ((l >> 4) * 8);
        int n = 16 * t + (l & 15);
#pragma unroll
        for (int j = 0; j < 8; ++j) {
            int k = kbase + j;
            float w = transposed ? W[n * K + k] : W[k * D + n];
            out[(size_t)cl * 8 + j] = __hip_bfloat16_raw(__float2bfloat16(w)).x;
        }
    }
}

// ---------------- bucket sums: one block per (type,bucket) ----------------
__global__ __launch_bounds__(256) void bsum_kernel(const int* __restrict__ counts,
                                                   int* __restrict__ bsum, int N, int NB) {
    int b = blockIdx.x;
    int type = b / NB, bb = b - type * NB;
    int base = bb << BSH;
    int tid = threadIdx.x;
    int lane = tid & 63, wv = tid >> 6;
    int s = 0;
#pragma unroll
    for (int q = 0; q < (1 << BSH) / 256; ++q) {
        int n = base + q * 256 + tid;
        if (n < N) s += counts[type * N + n];
    }
#pragma unroll
    for (int d = 1; d < 64; d <<= 1) s += __shfl_xor(s, d, 64);
    __shared__ int wsum[4];
    if (lane == 0) wsum[wv] = s;
    __syncthreads();
    if (tid == 0) bsum[b] = wsum[0] + wsum[1] + wsum[2] + wsum[3];
}

// ---------------- bucket scan: exclusive scan of bucket sums per type ----------------
// Writes bbase (bucket csr start, read-only after) and bcur (mutated by p1).
__global__ __launch_bounds__(64) void bscan_kernel(const int* __restrict__ bsum,
                                                   int* __restrict__ bbase,
                                                   int* __restrict__ bcur, int NB) {
    int type = blockIdx.x;
    int lane = threadIdx.x;
    int carry = 0;
    for (int c0 = 0; c0 < NB; c0 += 64) {
        int i = c0 + lane;
        int v = (i < NB) ? bsum[type * NB + i] : 0;
        int incl = v;
#pragma unroll
        for (int d = 1; d < 64; d <<= 1) {
            int t = __shfl_up(incl, d, 64);
            if (lane >= d) incl += t;
        }
        int excl = carry + incl - v;
        if (i < NB) {
            bbase[type * NB + i] = excl;
            bcur[type * NB + i] = excl;
        }
        carry += __shfl(incl, 63, 64);
    }
}

// ---------------- offsets: GLOBALLY SORTED (bucket base + in-bucket scan) ----------------
// R9's crash: the old one-atomic-per-wave offs was NOT sorted, so bucket
// regions weren't contiguous and scatter_p1 wrote staging out-of-bounds.
// Sorted offs makes bucket region == [bbase, bbase+sum) by construction.
__global__ __launch_bounds__(256) void offs_kernel(const int* __restrict__ counts,
                                                   const int* __restrict__ bbase,
                                                   int* __restrict__ offs, int N, int NB) {
    int b = blockIdx.x;
    int type = b / NB, bb = b - type * NB;
    int base = bb << BSH;
    int tid = threadIdx.x;
    int lane = tid & 63, wv = tid >> 6;
    int n0 = base + tid * 4;
    int v[4];
    int s = 0;
#pragma unroll
    for (int j = 0; j < 4; ++j) {
        int n = n0 + j;
        v[j] = (n < N) ? counts[type * N + n] : 0;
        s += v[j];
    }
    int incl = s;
#pragma unroll
    for (int d = 1; d < 64; d <<= 1) {
        int t = __shfl_up(incl, d, 64);
        if (lane >= d) incl += t;
    }
    __shared__ int wtot[4];
    if (lane == 63) wtot[wv] = incl;
    __syncthreads();
    int wbase = 0;
#pragma unroll
    for (int w = 0; w < 4; ++w)
        if (w < wv) wbase += wtot[w];
    int run = bbase[type * NB + bb] + wbase + incl - s;
#pragma unroll
    for (int j = 0; j < 4; ++j) {
        int n = n0 + j;
        if (n < N) offs[type * N + n] = run;
        run += v[j];
    }
}

// ---------------- scatter pass 1: bin edges into 1024-node buckets ----------------
// LDS histogram -> one global atomic per (block,bucket) -> burst writes fill
// each bucket region contiguously (line-dense). src<2^17, local-dst<2^10.
__global__ __launch_bounds__(256) void scatter_p1(
    const int* __restrict__ dst0, const int* __restrict__ src0,
    const int* __restrict__ dst1, const int* __restrict__ src1,
    const int* __restrict__ dst2, const int* __restrict__ src2,
    int* __restrict__ bcur, unsigned* __restrict__ stg0,
    u64* __restrict__ stg1, u64* __restrict__ stg2, int E, int NB, int bpt1) {
    int bid = blockIdx.x, tid = threadIdx.x;
    int type, blk;
    if (bid < bpt1) { type = 0; blk = bid; }
    else if (bid < 2 * bpt1) { type = 1; blk = bid - bpt1; }
    else { type = 2; blk = bid - 2 * bpt1; }
    const int* dst = (type == 0) ? dst0 : (type == 1) ? dst1 : dst2;

    __shared__ int hist[MAXNB];
    __shared__ int basesh[MAXNB];
    if (tid < NB) hist[tid] = 0;
    __syncthreads();

    const int e0 = blk * 4096;
    int rank[16], bkt[16], ld[16];
#pragma unroll
    for (int k = 0; k < 16; ++k) {
        int e = e0 + k * 256 + tid;
        bkt[k] = -1;
        if (e < E) {
            int d = __builtin_nontemporal_load(dst + e);
            int bb = d >> BSH;
            bkt[k] = bb;
            ld[k] = d & ((1 << BSH) - 1);
            rank[k] = atomicAdd(&hist[bb], 1);
        }
    }
    __syncthreads();
    if (tid < NB) {
        int h = hist[tid];
        if (h > 0) basesh[tid] = atomicAdd(&bcur[type * NB + tid], h);
    }
    __syncthreads();
#pragma unroll
    for (int k = 0; k < 16; ++k) {
        if (bkt[k] >= 0) {
            int e = e0 + k * 256 + tid;
            int pos = basesh[bkt[k]] + rank[k];
            if (type == 0) {
                unsigned s = (unsigned)__builtin_nontemporal_load(src0 + e);
                stg0[pos] = ((unsigned)ld[k] << 17) | s;
            } else if (type == 1) {
                int2 s = *(const int2*)(src1 + 2 * (size_t)e);
                u64 u = (u64)(unsigned)s.x | ((u64)(unsigned)s.y << 17) |
                        ((u64)(unsigned)ld[k] << 34);
                stg1[pos] = u;
            } else {
                int s0 = __builtin_nontemporal_load(src2 + 3 * (size_t)e);
                int s1 = __builtin_nontemporal_load(src2 + 3 * (size_t)e + 1);
                int s2 = __builtin_nontemporal_load(src2 + 3 * (size_t)e + 2);
                u64 u = (u64)(unsigned)s0 | ((u64)(unsigned)s1 << 17) |
                        ((u64)(unsigned)s2 << 34) | ((u64)(unsigned)ld[k] << 51);
                stg2[pos] = u;
            }
        }
    }
}

// ---------------- scatter pass 2: bucket -> exact CSR position ----------------
// One block per (bucket,type): node cursors in LDS (atomics ~free), csr write
// window 8-24 KB (L2-hot) -> dense evictions. csr semantics unchanged.
__global__ __launch_bounds__(256) void scatter_p2(
    const int* __restrict__ offs, const int* __restrict__ bbase,
    const int* __restrict__ bcur,
    const unsigned* __restrict__ stg0, const u64* __restrict__ stg1,
    const u64* __restrict__ stg2, int* __restrict__ csr0, int* __restrict__ csr1,
    int* __restrict__ csr2, int N, int NB) {
    int bb = blockIdx.x, tid = threadIdx.x;
    int type = 0;
    if (bb >= NB) { type = 1; bb -= NB; }
    if (bb >= NB) { type = 2; bb -= NB; }
    int base = bb << BSH;
    int nn = N - base;
    if (nn > (1 << BSH)) nn = 1 << BSH;

    __shared__ int cur[1 << BSH];
#pragma unroll
    for (int q = 0; q < (1 << BSH) / 256; ++q) {
        int i = q * 256 + tid;
        if (i < nn) cur[i] = offs[type * N + base + i];
    }
    __syncthreads();

    int bstart = bbase[type * NB + bb];
    int bend = bcur[type * NB + bb];  // final cursor after pass 1 == bucket end

    if (type == 0) {
        for (int e = bstart + tid; e < bend; e += 256) {
            unsigned u = stg0[e];
            int p = atomicAdd(&cur[u >> 17], 1);
            csr0[p] = (int)(u & 0x1FFFFu);
        }
    } else if (type == 1) {
        for (int e = bstart + tid; e < bend; e += 256) {
            u64 u = stg1[e];
            int p = atomicAdd(&cur[(int)(u >> 34)], 1);
            int2 o;
            o.x = (int)(u & 0x1FFFFu);
            o.y = (int)((u >> 17) & 0x1FFFFu);
            *(int2*)(csr1 + 2 * (size_t)p) = o;
        }
    } else {
        for (int e = bstart + tid; e < bend; e += 256) {
            u64 u = stg2[e];
            int p = atomicAdd(&cur[(int)(u >> 51)], 1);
            int4 o;
            o.x = (int)(u & 0x1FFFFu);
            o.y = (int)((u >> 17) & 0x1FFFFu);
            o.z = (int)((u >> 34) & 0x1FFFFu);
            o.w = 0;
            *(int4*)(csr2 + 4 * (size_t)p) = o;
        }
    }
}

// ---------------- per-node aggregation (R7 form, probe-confirmed at roofline) ----------------
template <int A>
__device__ inline void agg_wave(const u16* __restrict__ xb, const int* __restrict__ csr,
                                int o0, int deg, int lane, u16* __restrict__ outp) {
    constexpr int ST = (A == 3) ? 4 : A;  // csr stride per edge (csr2 padded)
    constexpr int CH_E = (A == 1) ? 12 : (A == 2) ? 10 : 8;  // edges per chunk
    constexpr int CH = CH_E * ST;
    floatx2 acc[A];
#pragma unroll
    for (int s = 0; s < A; ++s) acc[s] = floatx2{0.f, 0.f};
    const int base = o0 * ST;
    const int last = base + deg * ST - 1;
    const unsigned* __restrict__ xw = (const unsigned*)xb;

    for (int e0 = 0; e0 < deg; e0 += CH_E) {
        int rv = 0;
        if (lane < CH) {
            int idx = base + e0 * ST + lane;
            if (idx > last) idx = last;  // clamp, never guard
            rv = csr[idx];
        }
        int erem = deg - e0;  // wave-uniform
        unsigned u[CH_E][A];
#pragma unroll
        for (int ke = 0; ke < CH_E; ++ke)
#pragma unroll
            for (int s = 0; s < A; ++s) {
                int r = __builtin_amdgcn_readlane(rv, ke * ST + s);  // SGPR row id
                u[ke][s] = xw[((size_t)(unsigned)r << 6) + lane];
            }
        if (erem >= CH_E) {
#pragma unroll
            for (int ke = 0; ke < CH_E; ++ke)
#pragma unroll
                for (int s = 0; s < A; ++s) {
                    floatx2 f = {bflo(u[ke][s]), bfhi(u[ke][s])};
                    acc[s] += f;
                }
        } else {
#pragma unroll
            for (int ke = 0; ke < CH_E; ++ke) {
                bool ok = ke < erem;
#pragma unroll
                for (int s = 0; s < A; ++s) {
                    unsigned uz = ok ? u[ke][s] : 0u;
                    floatx2 f = {bflo(uz), bfhi(uz)};
                    acc[s] += f;
                }
            }
        }
    }

    float norm = (deg > 0) ? 1.0f / (float)deg : 0.0f;
#pragma unroll
    for (int s = 0; s < A; ++s) {
        unsigned o = packbf(acc[s].x * norm, acc[s].y * norm);
        ((unsigned*)(outp + s * D))[lane] = o;
    }
}

__global__ __launch_bounds__(256) void aggregate_kernel(
    const u16* __restrict__ xb, const int* __restrict__ counts, const int* __restrict__ offs,
    const int* __restrict__ csr0, const int* __restrict__ csr1, const int* __restrict__ csr2,
    u16* __restrict__ AG, int n0, int M, int N) {
    int w = __builtin_amdgcn_readfirstlane(threadIdx.x >> 6);
    int gw = blockIdx.x * 4 + w;
    int lane = threadIdx.x & 63;
    if (gw >= 3 * M) return;
    int type = (gw >= 2 * M) ? 2 : (gw >= M) ? 1 : 0;
    int l = gw - type * M;
    int n = n0 + l;
    u16* outp = AG + (size_t)l * 768;
    if (type == 0) {
        int o0 = __builtin_amdgcn_readfirstlane(offs[n]);
        int dg = __builtin_amdgcn_readfirstlane(counts[n]);
        agg_wave<1>(xb, csr0, o0, dg, lane, outp);
    } else if (type == 1) {
        int o0 = __builtin_amdgcn_readfirstlane(offs[N + n]);
        int dg = __builtin_amdgcn_readfirstlane(counts[N + n]);
        agg_wave<2>(xb, csr1, o0, dg, lane, outp + 128);
    } else {
        int o0 = __builtin_amdgcn_readfirstlane(offs[2 * N + n]);
        int dg = __builtin_amdgcn_readfirstlane(counts[2 * N + n]);
        agg_wave<3>(xb, csr2, o0, dg, lane, outp + 384);
    }
}

// ---------------- fused final GEMM (R7 form: LDS dbuf + reg prefetch, 1 barrier) ----------------
__global__ __launch_bounds__(256) void final_gemm_kernel(
    const u16* __restrict__ xb, const u16* __restrict__ AG, const u16* __restrict__ Wp,
    const float* __restrict__ bC, float* __restrict__ out, int n0, int M) {
    constexpr int KSTEPS = 14;  // 896 / 64
    alignas(16) __shared__ u16 As[2][128][72];

    const int tid = threadIdx.x;
    const int wave = tid >> 6;
    const int lane = tid & 63;
    const int m0 = blockIdx.x * 128;

    floatx4 acc[2][8];
#pragma unroll
    for (int s = 0; s < 2; ++s)
#pragma unroll
        for (int t = 0; t < 8; ++t) acc[s][t] = floatx4{0.f, 0.f, 0.f, 0.f};

    auto ld = [&](int ks, int it) -> uintx4 {
        int chunk = tid + it * 256;
        int row = chunk >> 3, part = chunk & 7;
        int e = m0 + row;
        const u16* srcp;
        if (ks < 2) {
            int g = (e < M) ? (n0 + e) : n0;
            srcp = xb + (size_t)g * D + ks * 64;
        } else {
            int l = (e < M) ? e : 0;
            srcp = AG + (size_t)l * 768 + (ks - 2) * 64;
        }
        return *(const uintx4*)(srcp + part * 8);
    };

    uintx4 st[4];
#pragma unroll
    for (int it = 0; it < 4; ++it) st[it] = ld(0, it);

    for (int ks = 0; ks < KSTEPS; ++ks) {
        const int cur = ks & 1;
#pragma unroll
        for (int it = 0; it < 4; ++it) {
            int chunk = tid + it * 256;
            int row = chunk >> 3, part = chunk & 7;
            *(uintx4*)(&As[cur][row][part * 8]) = st[it];
        }
        if (ks < KSTEPS - 1) {
#pragma unroll
            for (int it = 0; it < 4; ++it) st[it] = ld(ks + 1, it);
        }
        __syncthreads();
#pragma unroll
        for (int sub = 0; sub < 2; ++sub) {
            bf16x8 bfrag[8];
#pragma unroll
            for (int t = 0; t < 8; ++t)
                bfrag[t] = *(const bf16x8*)(Wp + (size_t)ks * 8192 +
                                            ((size_t)((sub * 8 + t) * 64 + lane)) * 8);
#pragma unroll
            for (int strip = 0; strip < 2; ++strip) {
                int row = wave * 32 + strip * 16 + (lane & 15);
                bf16x8 afrag = *(const bf16x8*)(&As[cur][row][sub * 32 + ((lane >> 4) * 8)]);
#pragma unroll
                for (int t = 0; t < 8; ++t)
                    acc[strip][t] = __builtin_amdgcn_mfma_f32_16x16x32_bf16(
                        afrag, bfrag[t], acc[strip][t], 0, 0, 0);
            }
        }
    }

#pragma unroll
    for (int strip = 0; strip < 2; ++strip) {
#pragma unroll
        for (int r = 0; r < 4; ++r) {
            int row = wave * 32 + strip * 16 + (lane >> 4) * 4 + r;
            int e = m0 + row;
            if (e >= M) continue;
            size_t base = (size_t)(n0 + e) * D;
#pragma unroll
            for (int t = 0; t < 8; ++t) {
                int col = 16 * t + (lane & 15);
                out[base + col] = acc[strip][t][r] + bC[col];
            }
        }
    }
}

extern "C" void kernel_launch(void* const* d_in, const int* in_sizes, int n_in,
                              void* d_out, int out_size, void* d_ws, size_t ws_size,
                              hipStream_t stream) {
    const float* x = (const float*)d_in[0];
    const int* src0 = (const int*)d_in[1];
    const int* dst0 = (const int*)d_in[2];
    const int* src1 = (const int*)d_in[3];
    const int* dst1 = (const int*)d_in[4];
    const int* src2 = (const int*)d_in[5];
    const int* dst2 = (const int*)d_in[6];
    const float* WA0 = (const float*)d_in[7];
    const float* WA1 = (const float*)d_in[8];
    const float* WA2 = (const float*)d_in[9];
    const float* WC = (const float*)d_in[10];
    const float* bC = (const float*)d_in[11];

    const int N = in_sizes[0] / D;  // 100000
    const int E = in_sizes[2];      // 500000
    const int NB = (N + (1 << BSH) - 1) >> BSH;  // 98

    auto align256 = [](size_t v) { return (v + 255) & ~(size_t)255; };
    char* ws = (char*)d_ws;
    size_t ofs = 0;
    u16* xb = (u16*)(ws + ofs);      ofs = align256(ofs + (size_t)N * D * sizeof(u16));
    int* counts = (int*)(ws + ofs);  ofs = align256(ofs + (size_t)3 * N * sizeof(int));
    int* offs = (int*)(ws + ofs);    ofs = align256(ofs + (size_t)3 * N * sizeof(int));
    int* bsum = (int*)(ws + ofs);    ofs = align256(ofs + (size_t)3 * MAXNB * sizeof(int));
    int* bbase = (int*)(ws + ofs);   ofs = align256(ofs + (size_t)3 * MAXNB * sizeof(int));
    int* bcur = (int*)(ws + ofs);    ofs = align256(ofs + (size_t)3 * MAXNB * sizeof(int));
    int* csr0 = (int*)(ws + ofs);    // E ints
    int* csr1 = csr0 + E;            // 2E ints
    int* csr2 = csr1 + 2 * E;        // 4E ints (stride-4 padded)
    ofs = align256(ofs + (size_t)7 * E * sizeof(int));
    unsigned* stg0 = (unsigned*)(ws + ofs); ofs = align256(ofs + (size_t)E * sizeof(unsigned));
    u64* stg1 = (u64*)(ws + ofs);    ofs = align256(ofs + (size_t)E * sizeof(u64));
    u64* stg2 = (u64*)(ws + ofs);    ofs = align256(ofs + (size_t)E * sizeof(u64));
    u16* Wp = (u16*)(ws + ofs);      ofs = align256(ofs + (size_t)896 * D * sizeof(u16));
    u16* AG = (u16*)(ws + ofs);

    size_t avail = (ws_size > ofs) ? (ws_size - ofs) : 0;
    long long ncMax = (long long)(avail / (768 * sizeof(u16)));
    int Nc = (int)((ncMax / 128) * 128);
    if (Nc > N) Nc = ((N + 127) / 128) * 128;
    if (Nc < 128) Nc = 128;

    // prep
    zero_int_kernel<<<512, 256, 0, stream>>>(counts, 3 * N);

    int cb3 = (3 * E + 255) / 256;
    int packb = (14336 + 255) / 256;  // 56
    prep_kernel<<<CVB + cb3 + packb, 256, 0, stream>>>(x, xb, N * D / 4,
                                                       dst0, dst1, dst2, counts, E, N, cb3,
                                                       WC, WA0, WA1, WA2, Wp);

    bsum_kernel<<<3 * NB, 256, 0, stream>>>(counts, bsum, N, NB);
    bscan_kernel<<<3, 64, 0, stream>>>(bsum, bbase, bcur, NB);
    offs_kernel<<<3 * NB, 256, 0, stream>>>(counts, bbase, offs, N, NB);

    int bpt1 = (E + 4095) / 4096;
    scatter_p1<<<3 * bpt1, 256, 0, stream>>>(dst0, src0, dst1, src1, dst2, src2,
                                             bcur, stg0, stg1, stg2, E, NB, bpt1);
    scatter_p2<<<3 * NB, 256, 0, stream>>>(offs, bbase, bcur, stg0, stg1, stg2,
                                           csr0, csr1, csr2, N, NB);

    for (int n0 = 0; n0 < N; n0 += Nc) {
        int M = (N - n0 < Nc) ? (N - n0) : Nc;
        int ab = (3 * M + 3) / 4;
        aggregate_kernel<<<ab, 256, 0, stream>>>(xb, counts, offs, csr0, csr1, csr2,
                                                 AG, n0, M, N);
        final_gemm_kernel<<<(M + 127) / 128, 256, 0, stream>>>(xb, AG, Wp, bC,
                                                               (float*)d_out, n0, M);
    }
}